// Round 17
// baseline (132.791 us; speedup 1.0000x reference)
//
#include <hip/hip_runtime.h>
#include <math.h>

// Problem constants (from reference)
#define NDIM   8
#define NBINS  64
#define LOG_BETA   (-13.815510557964274f)  // log(1e-6)
#define LN2F       0.69314718055994531f
// mesh is geometric: boundary_j (original coords) = x1L*(1.2^j-1)/0.2, j=0..32
// bin index from |x|: g = log2(1 + ALPHA*|x|) / log2(1.2);  ALPHA = (1.2^32-1)/10
#define ALPHA      34.0821892f
#define INV_LOG2R  3.80178401692393f       // 1/log2(1.2)
#define L2R        0.26303440583379378f    // log2(1.2)
#define XMS        0.0014670379f           // 0.05/ALPHA == 0.5/(1.2^32-1)

typedef float f32x4 __attribute__((ext_vector_type(4)));

// Two threads per point: lane g handles float4 half (g&1) of point (g>>1).
// Skeleton = round-16 winner (39.5us). SINGLE CHANGE: the per-dim table
// gather shrinks from one ds_read_b128 {v1,slope,Fpre,mesh} to ds_read_b64
// {v1,slope} + ds_read_b32 {Fpre}; mesh_k is computed ANALYTICALLY:
//   xm = (u - r^jf)*XMS   (x>=0),   xm = (r^(jf+1) - u)*XMS   (x<0)
// with u = 1+ALPHA*|x| (already computed for the log2) and one exp2f that
// runs in parallel with the LDS fetch. b128 random-k gathers have >=8-way
// inherent bank-group aliasing (16B/lane over 32 banks); b64 is 4-way and
// b32 2-way (free) — attacks the 1.6M conflict-cycles + shortens the
// post-load dependent chain.
__global__ __launch_bounds__(512, 4) void cdfq_fused(const float* __restrict__ x,
                                                     const float* __restrict__ logdet_in,
                                                     const float* __restrict__ p,
                                                     float* __restrict__ y_out,
                                                     float* __restrict__ ld_out,
                                                     int n)
{
    __shared__ float2 vs_tbl[NDIM * NBINS];  // [d][k]: {v1, slope}
    __shared__ float  fp_tbl[NDIM * NBINS];  // [d][k]: F_pre

    const int t  = threadIdx.x;
    const int T  = gridDim.x * blockDim.x;         // work-item stride
    const int i0 = blockIdx.x * blockDim.x + t;
    const int G  = 2 * n;                          // work items = half-points
    const int iters = G / T;                       // 8 on the bench shape
    const f32x4* xv4 = (const f32x4*)x;

    // ---- prologue: 3-deep prefetch issued BEFORE prep so the first three
    //      memory latencies hide behind prep's VALU/shuffle work ----
    f32x4 X0, X1, X2; float L0, L1, Lc2;
    if (iters > 0) { X0 = xv4[i0];         L0  = logdet_in[i0 >> 1]; }
    if (iters > 1) { X1 = xv4[i0 + T];     L1  = logdet_in[(i0 + T) >> 1]; }
    if (iters > 2) { X2 = xv4[i0 + 2 * T]; Lc2 = logdet_in[(i0 + 2 * T) >> 1]; }
    __builtin_amdgcn_sched_barrier(0);   // do not sink these below prep

    // ---- prep: 8 waves, each builds ONE dim of the table fully in-register.
    //      Serial chain: exp -> a -> scan(6) -> bcast -> scale -> write. ----
    {
        const int lane = t & 63;
        const int d    = t >> 6;                   // wave index == dim, 0..7
        const float pw32 = exp2f(32.0f * L2R);     // 1.2^32
        const float inv  = 0.5f / (pw32 - 1.0f);
        auto meshf = [&](float tt) {               // normalized mesh coordinate
            float fidx = tt - 32.0f;
            float pw = exp2f(fabsf(fidx) * L2R);
            float r  = (pw - 1.0f) * inv;
            return 0.5f + ((fidx >= 0.0f) ? r : -r);
        };
        const float m0  = meshf((float)lane);          // mesh[lane]
        const float m1  = meshf((float)(lane + 1));    // mesh[lane+1]
        const float el  = m1 - m0;                     // elmt[lane]
        const float e0e63 = 2.0f * (meshf(1.0f) - meshf(0.0f)); // elmt[0]+elmt[63]

        float ep = 0.0f;
        if (lane < 63) ep = __expf(p[lane * NDIM + d]);  // interior node lane+1
        float epu = __shfl_up(ep, 1);
        if (lane == 0) epu = 0.0f;                       // no interior node at 0

        // unscaled cell integral (variable part): a_k = el_k*(ep_{k-1}+ep_k)/2
        const float a = 0.5f * el * (epu + ep);
        // inclusive scan of a
        float v = a;
#pragma unroll
        for (int off = 1; off < 64; off <<= 1) {
            float u = __shfl_up(v, off);
            if (lane >= off) v += u;
        }
        // lane 63 of the scan == Sum a_k == normalization sum s
        const float s = __shfl(v, 63);
        const float scale = (1.0f - e0e63 * 5e-7f) / s;
        // fixed beta-boundary part of the exclusive prefix (cell_0 only)
        const float b_pre = (lane > 0) ? (2.5e-7f * e0e63) : 0.0f;

        const float Fpre = fmaf(scale, v - a, b_pre);   // exclusive prefix, scaled
        const float pdl = (lane == 0)  ? 1e-6f : scale * epu;  // pdf[lane]
        const float pdn = (lane == 63) ? 1e-6f : scale * ep;   // pdf[lane+1]
        vs_tbl[(d << 6) | lane] = make_float2(pdl, (pdn - pdl) / el);
        fp_tbl[(d << 6) | lane] = Fpre;
    }
    __syncthreads();

    // ---- iteration-invariant hoists: half-point parity never changes ----
    const int  tbase    = ((i0 & 1) << 2) << 6;    // dims 0-3 or 4-7 base index
    const bool evenlane = ((i0 & 1) == 0);

    // ---- per-half-point body: 4 dims, one shfl_xor to combine logdet ----
    auto body = [&](f32x4 Xv, float Lin, int g) {
        float yd[4];
        float contrib;

        float mx = fmaxf(fmaxf(fabsf(Xv[0]), fabsf(Xv[1])),
                         fmaxf(fabsf(Xv[2]), fabsf(Xv[3])));

        if (!__any(mx >= 10.0f)) {
            // ---- fast path (always taken for N(0,1) input) ----
            float dd4[4];
#pragma unroll
            for (int dl = 0; dl < 4; ++dl) {
                float xo = Xv[dl];
                float u  = fmaf(ALPHA, fabsf(xo), 1.0f);
                float gg = __log2f(u) * INV_LOG2R;       // one v_log_f32
                int jf = (int)fminf(gg, 31.0f);
                bool pos = (xo >= 0.0f);
                int k  = (pos ? 32 : 31) ^ jf;           // 32+jf / 31-jf
                int idx = tbase + (dl << 6) + k;

                float rj = exp2f((float)jf * L2R);       // r^jf, parallel w/ LDS
                float2 vs = vs_tbl[idx];                 // ds_read_b64
                float  Fp = fp_tbl[idx];                 // ds_read_b32
                // analytic in-bin offset (== xs - mesh_k to rounding)
                float xm = (pos ? (u - rj) : fmaf(1.2f, rj, -u)) * XMS;

                yd[dl]  = fmaf(fmaf(xm, fmaf(0.5f * xm, vs.y, vs.x), Fp),
                               20.0f, -10.0f);
                dd4[dl] = fmaf(xm, vs.y, vs.x);
            }
            contrib = (__log2f(dd4[0] * dd4[1]) + __log2f(dd4[2] * dd4[3])) * LN2F;
        } else {
            // ---- full reference path (rare) ----
            float dd4[4];
            float extra = 0.0f;
#pragma unroll
            for (int dl = 0; dl < 4; ++dl) {
                float xo = Xv[dl];
                float xs = fmaf(xo, 0.05f, 0.5f);
                float u  = fmaf(ALPHA, fabsf(xo), 1.0f);
                float gg = __log2f(u) * INV_LOG2R;
                int jf = (int)fminf(gg, 31.0f);
                bool pos = (xo >= 0.0f);
                int k  = (pos ? 32 : 31) ^ jf;
                int idx = tbase + (dl << 6) + k;

                float rj = exp2f((float)jf * L2R);
                float2 vs = vs_tbl[idx];
                float  Fp = fp_tbl[idx];
                float xm = (pos ? (u - rj) : fmaf(1.2f, rj, -u)) * XMS;
                bool cov = (fabsf(xo) < 10.0f);          // == (0 <= xs < 1)

                float yc = fmaf(xm, fmaf(0.5f * xm, vs.y, vs.x), Fp);
                float dv = fmaf(xm, vs.y, vs.x);
                float yy = cov ? yc : xs;
                dd4[dl]  = cov ? dv : 1.0f;

                yy = fmaf(yy, 20.0f, -10.0f);
                if (yy > 10.0f)  { yy = fmaf(1e-6f, yy - 10.0f, 10.0f);  extra += LOG_BETA; }
                if (yy < -10.0f) { yy = fmaf(1e-6f, yy + 10.0f, -10.0f); extra += LOG_BETA; }
                yd[dl] = yy;
            }
            contrib = fmaf(__log2f(dd4[0] * dd4[1]) + __log2f(dd4[2] * dd4[3]),
                           LN2F, extra);
        }

        float cross = __shfl_xor(contrib, 1);      // partner half-point (DPP)

        f32x4 yv = { yd[0], yd[1], yd[2], yd[3] };
        *((f32x4*)y_out + g) = yv;                 // PLAIN store (acks at L2)
        if (evenlane)
            ld_out[g >> 1] = Lin + contrib + cross;
    };

    // ---- main loop: guard-free 4-stage (3 loads in flight) software pipeline ----
    for (int j = 0; j < iters; ++j) {
        f32x4 Xn; float Ln;
        const bool more = (j + 3 < iters);         // wave-uniform
        if (more) {
            int gx = i0 + (j + 3) * T;
            Xn = xv4[gx];
            Ln = logdet_in[gx >> 1];
        }
        __builtin_amdgcn_sched_barrier(0);         // keep prefetch above the compute

        body(X0, L0, i0 + j * T);

        X0 = X1; L0 = L1;
        X1 = X2; L1 = Lc2;
        if (more) { X2 = Xn; Lc2 = Ln; }
    }

    // ---- remainder (never runs when T | G; kept for generality) ----
    for (int g = i0 + iters * T; g < G; g += T) {
        body(xv4[g], logdet_in[g >> 1], g);        // pairs never split: G is even,
                                                   // partner is adjacent lane
    }
}

extern "C" void kernel_launch(void* const* d_in, const int* in_sizes, int n_in,
                              void* d_out, int out_size, void* d_ws, size_t ws_size,
                              hipStream_t stream) {
    const float* x      = (const float*)d_in[0];   // [N, 8]
    const float* logdet = (const float*)d_in[1];   // [N, 1]
    const float* p      = (const float*)d_in[2];   // [63, 8]

    const int n = in_sizes[1];                     // N points
    float* y_out  = (float*)d_out;                 // [N*8]
    float* ld_out = (float*)d_out + (size_t)n * NDIM;  // [N]

    const int block = 512;
    int grid = 1024;                               // T=524288 (iters=8), 4 blk/CU
                                                   // x 8 waves = 32 waves/CU
    if ((long long)grid * block > 2LL * n) grid = (2 * n + block - 1) / block;
    cdfq_fused<<<grid, block, 0, stream>>>(x, logdet, p, y_out, ld_out, n);
}

// Round 18
// 129.454 us; speedup vs baseline: 1.0258x; 1.0258x over previous
//
#include <hip/hip_runtime.h>
#include <math.h>

// Problem constants (from reference)
#define NDIM   8
#define NBINS  64
#define LOG_BETA   (-13.815510557964274f)  // log(1e-6)
#define LN2F       0.69314718055994531f
// mesh is geometric: boundary_j (original coords) = x1L*(1.2^j-1)/0.2, j=0..32
// bin index from |x|: g = log2(1 + ALPHA*|x|) / log2(1.2);  ALPHA = (1.2^32-1)/10
#define ALPHA      34.0821892f
#define INV_LOG2R  3.80178401692393f       // 1/log2(1.2)
#define L2R        0.26303440583379378f    // log2(1.2)

typedef float f32x4 __attribute__((ext_vector_type(4)));

// Two threads per point: lane g handles float4 half (g&1) of point (g>>1).
// Skeleton = round-16 winner (39.5us kernel: 512-thr blocks, 1 dim/wave
// scan-identity prep, plain stores, 3-deep prefetch, b128 table). SINGLE
// CHANGE vs R16: __builtin_nontemporal_load on the x/logdet streams (read
// exactly once per dispatch). Theory: 75 MB of read-once L2 allocations
// thrash the 32 MB L2 against the 74 MB write stream whose fast L2 acks the
// loop depends on (R12). NT loads skip L2 allocate (L3 still serves the
// cross-dispatch re-reads), freeing L2 for the write stream.
__global__ __launch_bounds__(512, 4) void cdfq_fused(const float* __restrict__ x,
                                                     const float* __restrict__ logdet_in,
                                                     const float* __restrict__ p,
                                                     float* __restrict__ y_out,
                                                     float* __restrict__ ld_out,
                                                     int n)
{
    __shared__ float4 stbl[NDIM * NBINS];  // [d][k]: {v1, slope, F_pre, mesh_k}

    const int t  = threadIdx.x;
    const int T  = gridDim.x * blockDim.x;         // work-item stride
    const int i0 = blockIdx.x * blockDim.x + t;
    const int G  = 2 * n;                          // work items = half-points
    const int iters = G / T;                       // 8 on the bench shape
    const f32x4* xv4 = (const f32x4*)x;

    // ---- prologue: 3-deep prefetch issued BEFORE prep so the first three
    //      memory latencies hide behind prep's VALU/shuffle work ----
    f32x4 X0, X1, X2; float L0, L1, Lc2;
    if (iters > 0) { X0 = __builtin_nontemporal_load(xv4 + i0);
                     L0 = __builtin_nontemporal_load(logdet_in + (i0 >> 1)); }
    if (iters > 1) { X1 = __builtin_nontemporal_load(xv4 + i0 + T);
                     L1 = __builtin_nontemporal_load(logdet_in + ((i0 + T) >> 1)); }
    if (iters > 2) { X2 = __builtin_nontemporal_load(xv4 + i0 + 2 * T);
                     Lc2 = __builtin_nontemporal_load(logdet_in + ((i0 + 2 * T) >> 1)); }
    __builtin_amdgcn_sched_barrier(0);   // do not sink these below prep

    // ---- prep: 8 waves, each builds ONE dim of the table fully in-register.
    //      Serial chain: exp -> a -> scan(6) -> bcast -> scale -> write.
    //      (Scan identity: lane 63 of the inclusive scan == normalization sum.)
    {
        const int lane = t & 63;
        const int d    = t >> 6;                   // wave index == dim, 0..7
        const float pw32 = exp2f(32.0f * L2R);     // 1.2^32
        const float inv  = 0.5f / (pw32 - 1.0f);
        auto meshf = [&](float tt) {               // normalized mesh coordinate
            float fidx = tt - 32.0f;
            float pw = exp2f(fabsf(fidx) * L2R);
            float r  = (pw - 1.0f) * inv;
            return 0.5f + ((fidx >= 0.0f) ? r : -r);
        };
        const float m0  = meshf((float)lane);          // mesh[lane]
        const float m1  = meshf((float)(lane + 1));    // mesh[lane+1]
        const float el  = m1 - m0;                     // elmt[lane]
        const float e0e63 = 2.0f * (meshf(1.0f) - meshf(0.0f)); // elmt[0]+elmt[63]

        float ep = 0.0f;
        if (lane < 63) ep = __expf(p[lane * NDIM + d]);  // interior node lane+1
        float epu = __shfl_up(ep, 1);
        if (lane == 0) epu = 0.0f;                       // no interior node at 0

        // unscaled cell integral (variable part): a_k = el_k*(ep_{k-1}+ep_k)/2
        const float a = 0.5f * el * (epu + ep);
        // inclusive scan of a
        float v = a;
#pragma unroll
        for (int off = 1; off < 64; off <<= 1) {
            float u = __shfl_up(v, off);
            if (lane >= off) v += u;
        }
        // lane 63 of the scan == Sum a_k == normalization sum s
        const float s = __shfl(v, 63);
        const float scale = (1.0f - e0e63 * 5e-7f) / s;
        // fixed beta-boundary part of the exclusive prefix (cell_0 only)
        const float b_pre = (lane > 0) ? (2.5e-7f * e0e63) : 0.0f;

        const float Fpre = fmaf(scale, v - a, b_pre);   // exclusive prefix, scaled
        const float pdl = (lane == 0)  ? 1e-6f : scale * epu;  // pdf[lane]
        const float pdn = (lane == 63) ? 1e-6f : scale * ep;   // pdf[lane+1]
        stbl[(d << 6) | lane] = make_float4(pdl, (pdn - pdl) / el, Fpre, m0);
    }
    __syncthreads();

    // ---- iteration-invariant hoists: half-point parity never changes ----
    const float4* tbl = &stbl[((i0 & 1) << 2) << 6];   // dims 0-3 or 4-7 base
    const bool evenlane = ((i0 & 1) == 0);

    // ---- per-half-point body: 4 dims, one shfl_xor to combine logdet ----
    auto body = [&](f32x4 Xv, float Lin, int g) {
        float yd[4];
        float contrib;

        float mx = fmaxf(fmaxf(fabsf(Xv[0]), fabsf(Xv[1])),
                         fmaxf(fabsf(Xv[2]), fabsf(Xv[3])));

        if (!__any(mx >= 10.0f)) {
            // ---- fast path (always taken for N(0,1) input): no boundary
            //      handling, no cov selects, no LOG_BETA bookkeeping ----
            float dd4[4];
#pragma unroll
            for (int dl = 0; dl < 4; ++dl) {
                float xo = Xv[dl];
                float xs = fmaf(xo, 0.05f, 0.5f);        // (x+10)/20 to 1 ulp
                // analytic bin: one v_log_f32
                float gg = __log2f(fmaf(ALPHA, fabsf(xo), 1.0f)) * INV_LOG2R;
                int jf = (int)fminf(gg, 31.0f);
                int k  = ((xo >= 0.0f) ? 32 : 31) ^ jf;  // 32+jf / 31-jf

                f32x4 tv = *(const f32x4*)&tbl[(dl << 6) + k];
                float xm = xs - tv[3];
                yd[dl]  = fmaf(fmaf(xm, fmaf(0.5f * xm, tv[1], tv[0]), tv[2]),
                               20.0f, -10.0f);
                dd4[dl] = fmaf(xm, tv[1], tv[0]);
            }
            contrib = (__log2f(dd4[0] * dd4[1]) + __log2f(dd4[2] * dd4[3])) * LN2F;
        } else {
            // ---- full reference path (rare) ----
            float dd4[4];
            float extra = 0.0f;
#pragma unroll
            for (int dl = 0; dl < 4; ++dl) {
                float xo = Xv[dl];
                float xs = fmaf(xo, 0.05f, 0.5f);
                float gg = __log2f(fmaf(ALPHA, fabsf(xo), 1.0f)) * INV_LOG2R;
                int jf = (int)fminf(gg, 31.0f);
                int k  = ((xo >= 0.0f) ? 32 : 31) ^ jf;

                f32x4 tv = *(const f32x4*)&tbl[(dl << 6) + k];
                float xm = xs - tv[3];
                bool cov = (fabsf(xo) < 10.0f);          // == (0 <= xs < 1)

                float yc = fmaf(xm, fmaf(0.5f * xm, tv[1], tv[0]), tv[2]);
                float dv = fmaf(xm, tv[1], tv[0]);
                float yy = cov ? yc : xs;
                dd4[dl]  = cov ? dv : 1.0f;

                yy = fmaf(yy, 20.0f, -10.0f);
                if (yy > 10.0f)  { yy = fmaf(1e-6f, yy - 10.0f, 10.0f);  extra += LOG_BETA; }
                if (yy < -10.0f) { yy = fmaf(1e-6f, yy + 10.0f, -10.0f); extra += LOG_BETA; }
                yd[dl] = yy;
            }
            contrib = fmaf(__log2f(dd4[0] * dd4[1]) + __log2f(dd4[2] * dd4[3]),
                           LN2F, extra);
        }

        float cross = __shfl_xor(contrib, 1);      // partner half-point

        f32x4 yv = { yd[0], yd[1], yd[2], yd[3] };
        *((f32x4*)y_out + g) = yv;                 // PLAIN store (acks at L2)
        if (evenlane)
            ld_out[g >> 1] = Lin + contrib + cross;
    };

    // ---- main loop: guard-free 4-stage (3 loads in flight) software pipeline ----
    for (int j = 0; j < iters; ++j) {
        f32x4 Xn; float Ln;
        const bool more = (j + 3 < iters);         // wave-uniform
        if (more) {
            int gx = i0 + (j + 3) * T;
            Xn = __builtin_nontemporal_load(xv4 + gx);
            Ln = __builtin_nontemporal_load(logdet_in + (gx >> 1));
        }
        __builtin_amdgcn_sched_barrier(0);         // keep prefetch above the compute

        body(X0, L0, i0 + j * T);

        X0 = X1; L0 = L1;
        X1 = X2; L1 = Lc2;
        if (more) { X2 = Xn; Lc2 = Ln; }
    }

    // ---- remainder (never runs when T | G; kept for generality) ----
    for (int g = i0 + iters * T; g < G; g += T) {
        body(__builtin_nontemporal_load(xv4 + g),
             __builtin_nontemporal_load(logdet_in + (g >> 1)), g);
    }
}

extern "C" void kernel_launch(void* const* d_in, const int* in_sizes, int n_in,
                              void* d_out, int out_size, void* d_ws, size_t ws_size,
                              hipStream_t stream) {
    const float* x      = (const float*)d_in[0];   // [N, 8]
    const float* logdet = (const float*)d_in[1];   // [N, 1]
    const float* p      = (const float*)d_in[2];   // [63, 8]

    const int n = in_sizes[1];                     // N points
    float* y_out  = (float*)d_out;                 // [N*8]
    float* ld_out = (float*)d_out + (size_t)n * NDIM;  // [N]

    const int block = 512;
    int grid = 1024;                               // T=524288 (iters=8), 4 blk/CU
                                                   // x 8 waves = 32 waves/CU
    if ((long long)grid * block > 2LL * n) grid = (2 * n + block - 1) / block;
    cdfq_fused<<<grid, block, 0, stream>>>(x, logdet, p, y_out, ld_out, n);
}